// Round 1
// baseline (248.182 us; speedup 1.0000x reference)
//
#include <hip/hip_runtime.h>
#include <math.h>

// (B, N, D) = (16, 2048, 128)
constexpr int Bc = 16;
constexpr int Nc = 2048;
constexpr int Dc = 128;
constexpr int NCHUNK = Nc / 64;          // 32 key-chunks of 64
constexpr float SCALE_F = 0.08838834764831845f;  // 1/sqrt(128)

typedef __bf16 bf16x8 __attribute__((ext_vector_type(8)));
typedef __bf16 bf16x4 __attribute__((ext_vector_type(4)));
typedef float  f32x4  __attribute__((ext_vector_type(4)));

// ws layout: Kpack 8MB | Vpack 8MB | bias_sum 16MB
constexpr size_t KPACK_BYTES = (size_t)Bc * NCHUNK * 16 * 64 * 16;
constexpr size_t VPACK_BYTES = KPACK_BYTES;
constexpr size_t BIAS_BYTES  = (size_t)Nc * Nc * 4;
constexpr int CHUNK_ELEMS = 16 * 64 * 8;  // 8192 bf16 = 16KB per chunk

// ---- DPP 16-lane row reductions (VALU pipe, no LDS/lgkm) ----
template<int CTRL>
__device__ __forceinline__ float dpp_mv(float v) {
    return __builtin_bit_cast(float,
        __builtin_amdgcn_update_dpp(0, __builtin_bit_cast(int, v),
                                    CTRL, 0xF, 0xF, true));
}
__device__ __forceinline__ float rmax16(float v) {
    v = fmaxf(v, dpp_mv<0xB1>(v));
    v = fmaxf(v, dpp_mv<0x4E>(v));
    v = fmaxf(v, dpp_mv<0x141>(v));
    v = fmaxf(v, dpp_mv<0x140>(v));
    return v;
}
__device__ __forceinline__ float rsum16(float v) {
    v += dpp_mv<0xB1>(v);
    v += dpp_mv<0x4E>(v);
    v += dpp_mv<0x141>(v);
    v += dpp_mv<0x140>(v);
    return v;
}

// ---- fused prep: blocks [0,512) pack K/V, blocks [512,4608) sum biases ----
__global__ __launch_bounds__(256) void prep_fused(
    const float* __restrict__ K, const float* __restrict__ V,
    const int* __restrict__ imask,
    const float* __restrict__ b0, const float* __restrict__ b1,
    const float* __restrict__ b2, const float* __restrict__ b3,
    __bf16* __restrict__ Kp, __bf16* __restrict__ Vp, float* __restrict__ bs)
{
    __shared__ __align__(16) __bf16 Ks[64][136];
    __shared__ __align__(16) __bf16 Vs[64][136];
    const int bid = blockIdx.x;
    const int tid = threadIdx.x;

    if (bid >= 512) {
        const int i = (bid - 512) * 256 + tid;
        const float4 a = ((const float4*)b0)[i];
        const float4 c = ((const float4*)b1)[i];
        const float4 d = ((const float4*)b2)[i];
        const float4 e = ((const float4*)b3)[i];
        float4 r;
        r.x = a.x + c.x + d.x + e.x;
        r.y = a.y + c.y + d.y + e.y;
        r.z = a.z + c.z + d.z + e.z;
        r.w = a.w + c.w + d.w + e.w;
        ((float4*)bs)[i] = r;
        return;
    }

    const int c = bid & 31;
    const int b = bid >> 5;
    const int m0 = c * 64;
    const float* Kb = K + (size_t)b * Nc * Dc;
    const float* Vb = V + (size_t)b * Nc * Dc;
    const int* imb = imask + b * Nc;

    #pragma unroll
    for (int it = 0; it < 8; ++it) {
        const int idx = it * 256 + tid;
        const int row = idx >> 5;
        const int c4  = idx & 31;
        const int gm  = m0 + row;
        const float msk = imb[gm] ? 1.0f : 0.0f;
        const float4 kf = ((const float4*)(Kb + (size_t)gm * Dc))[c4];
        const float4 vf = ((const float4*)(Vb + (size_t)gm * Dc))[c4];
        bf16x4 kb, vb;
        kb[0] = (__bf16)(kf.x * msk); kb[1] = (__bf16)(kf.y * msk);
        kb[2] = (__bf16)(kf.z * msk); kb[3] = (__bf16)(kf.w * msk);
        vb[0] = (__bf16)(vf.x * msk); vb[1] = (__bf16)(vf.y * msk);
        vb[2] = (__bf16)(vf.z * msk); vb[3] = (__bf16)(vf.w * msk);
        *(bf16x4*)&Ks[row][c4 * 4] = kb;
        *(bf16x4*)&Vs[row][c4 * 4] = vb;
    }
    __syncthreads();

    const size_t chunk_base = (size_t)(b * NCHUNK + c) * CHUNK_ELEMS;
    #pragma unroll
    for (int i = 0; i < 4; ++i) {
        const int s = i * 256 + tid;
        const int f = s >> 6;
        const int l = s & 63;
        const int quad = (l >> 4) & 3;
        const int l15  = l & 15;
        {   // K frag f=jt*4+kd
            const int jt = f >> 2, kd = f & 3;
            const bf16x8 kv = *(const bf16x8*)&Ks[jt * 16 + l15][kd * 32 + quad * 8];
            *(bf16x8*)&Kp[chunk_base + (size_t)f * 512 + l * 8] = kv;
        }
        {   // V frag f=kj*8+dt
            const int kj = f >> 3, dt = f & 7;
            bf16x8 vv;
            #pragma unroll
            for (int j = 0; j < 8; ++j)
                vv[j] = Vs[kj * 32 + quad * 8 + j][dt * 16 + l15];
            *(bf16x8*)&Vp[chunk_base + (size_t)f * 512 + l * 8] = vv;
        }
    }
}

// ---- main: barrier-free per-wave flash attention ----
// grid (b=16, y=64), 128 threads = 2 independent waves per 32-row Q tile.
//  - waves split key-chunks even/odd (online softmax is associative); one
//    end-of-kernel merge combines the two partials -> no per-chunk barrier.
//  - K/V fragments read DIRECT from the L2-resident packs (per-XCD footprint
//    ~2.1MB < 4MB L2); no LDS staging, LDS only for P transpose + merge.
//  - 32 rows/wave: each K/V frag load feeds 2 MFMAs -> pack traffic halves
//    vs 16-row waves (540MB total ~ 16us at per-XCD L2 BW).
//  - all 1024 blocks resident (4/CU, 8 waves/CU, 28KB LDS, VGPR<=256);
//    tile permutation makes each CU's 4 tiles sum to a constant 66 chunks.
__global__ __launch_bounds__(128, 2) void attn_wave(
    const float* __restrict__ Q,
    const __bf16* __restrict__ Kp, const __bf16* __restrict__ Vp,
    const float* __restrict__ bias, const int* __restrict__ emask,
    float* __restrict__ out)
{
    __shared__ __align__(16) __bf16 Pl[2][32][72];   // per-wave P transpose
    __shared__ __align__(16) float  Olds[128][36];   // wave1 partial O
    __shared__ float Ml[32];
    __shared__ float Ll[32];

    const int tid  = threadIdx.x;
    const int w    = tid >> 6;
    const int lane = tid & 63;
    const int quad = lane >> 4;
    const int l15  = lane & 15;
    const int b = blockIdx.x;
    const int y = blockIdx.y;
    // Blocks {y, y+16, y+32, y+48} share a CU (ids differ by 256); this
    // permutation makes their chunk-counts sum to 66 for every y.
    const int t = (y < 32) ? y : ((y < 48) ? (79 - y) : (111 - y));
    const int r0 = t * 32;                 // tile rows [r0, r0+32)
    const int C  = (t >> 1) + 1;           // causal key-chunk count

    const float*  Qb  = Q  + (size_t)b * Nc * Dc;
    const __bf16* Kpb = Kp + (size_t)b * NCHUNK * CHUNK_ELEMS;
    const __bf16* Vpb = Vp + (size_t)b * NCHUNK * CHUNK_ELEMS;

    // ---- Q fragments for both 16-row halves (emask + SCALE folded) ----
    bf16x8 qf[2][4];
    #pragma unroll
    for (int h = 0; h < 2; ++h) {
        const int row = r0 + h * 16 + l15;
        const float qs = emask[b * Nc + row] ? SCALE_F : 0.0f;
        const float4* qr = (const float4*)(Qb + (size_t)row * Dc);
        #pragma unroll
        for (int kd = 0; kd < 4; ++kd) {
            const float4 xx = qr[kd * 8 + quad * 2];
            const float4 yy = qr[kd * 8 + quad * 2 + 1];
            qf[h][kd][0] = (__bf16)(xx.x * qs); qf[h][kd][1] = (__bf16)(xx.y * qs);
            qf[h][kd][2] = (__bf16)(xx.z * qs); qf[h][kd][3] = (__bf16)(xx.w * qs);
            qf[h][kd][4] = (__bf16)(yy.x * qs); qf[h][kd][5] = (__bf16)(yy.y * qs);
            qf[h][kd][6] = (__bf16)(yy.z * qs); qf[h][kd][7] = (__bf16)(yy.w * qs);
        }
    }

    // per-lane bias row pointers (row = r0 + 16h + quad*4 + reg, col base l15)
    const float* bp[2][4];
    #pragma unroll
    for (int h = 0; h < 2; ++h)
        #pragma unroll
        for (int reg = 0; reg < 4; ++reg)
            bp[h][reg] = bias + (size_t)(r0 + h * 16 + quad * 4 + reg) * Nc + l15;

    f32x4 oacc[2][8];
    float mrun[2][4], lrun[2][4];
    #pragma unroll
    for (int h = 0; h < 2; ++h) {
        #pragma unroll
        for (int dt = 0; dt < 8; ++dt) {
            oacc[h][dt][0] = 0.f; oacc[h][dt][1] = 0.f;
            oacc[h][dt][2] = 0.f; oacc[h][dt][3] = 0.f;
        }
        #pragma unroll
        for (int reg = 0; reg < 4; ++reg) { mrun[h][reg] = -INFINITY; lrun[h][reg] = 0.f; }
    }

    // wave w handles chunks c = w, w+2, ... (wave0 takes chunk 0 -> its
    // running max is always finite; wave1 may process zero chunks at t<2).
    for (int c = w; c < C; c += 2) {
        // bias loads (streamed once; nontemporal protects L2's K/V residency)
        float bc[2][4][4];
        #pragma unroll
        for (int h = 0; h < 2; ++h)
            #pragma unroll
            for (int jt = 0; jt < 4; ++jt)
                #pragma unroll
                for (int reg = 0; reg < 4; ++reg)
                    bc[h][jt][reg] = __builtin_nontemporal_load(bp[h][reg] + c * 64 + jt * 16);

        const size_t off = (size_t)c * CHUNK_ELEMS;

        // ---- QK: each K frag read once from L2, feeds both halves ----
        f32x4 sc[2][4];
        #pragma unroll
        for (int h = 0; h < 2; ++h)
            #pragma unroll
            for (int jt = 0; jt < 4; ++jt) {
                sc[h][jt][0] = 0.f; sc[h][jt][1] = 0.f;
                sc[h][jt][2] = 0.f; sc[h][jt][3] = 0.f;
            }
        #pragma unroll
        for (int jt = 0; jt < 4; ++jt)
            #pragma unroll
            for (int kd = 0; kd < 4; ++kd) {
                const bf16x8 kf = *(const bf16x8*)&Kpb[off + (size_t)(jt * 4 + kd) * 512 + lane * 8];
                sc[0][jt] = __builtin_amdgcn_mfma_f32_16x16x32_bf16(qf[0][kd], kf, sc[0][jt], 0, 0, 0);
                sc[1][jt] = __builtin_amdgcn_mfma_f32_16x16x32_bf16(qf[1][kd], kf, sc[1][jt], 0, 0, 0);
            }

        // ---- bias add (+ causal only on the diagonal chunk) ----
        if (c == C - 1) {
            #pragma unroll
            for (int h = 0; h < 2; ++h)
                #pragma unroll
                for (int jt = 0; jt < 4; ++jt)
                    #pragma unroll
                    for (int reg = 0; reg < 4; ++reg) {
                        const int gr = r0 + h * 16 + quad * 4 + reg;
                        const int gc = c * 64 + jt * 16 + l15;
                        const float v = sc[h][jt][reg] + bc[h][jt][reg];
                        sc[h][jt][reg] = (gc > gr) ? -INFINITY : v;
                    }
        } else {
            #pragma unroll
            for (int h = 0; h < 2; ++h)
                #pragma unroll
                for (int jt = 0; jt < 4; ++jt)
                    #pragma unroll
                    for (int reg = 0; reg < 4; ++reg)
                        sc[h][jt][reg] += bc[h][jt][reg];
        }

        // ---- online softmax per half; exact rescale-skip when no growth ----
        #pragma unroll
        for (int h = 0; h < 2; ++h) {
            float mx[4];
            int grow = 0;
            #pragma unroll
            for (int reg = 0; reg < 4; ++reg) {
                float m = fmaxf(fmaxf(sc[h][0][reg], sc[h][1][reg]),
                                fmaxf(sc[h][2][reg], sc[h][3][reg]));
                m = rmax16(m);
                mx[reg] = m;
                grow |= (m > mrun[h][reg]);
            }
            if (__any(grow)) {   // wave-uniform; skip path is numerically exact
                #pragma unroll
                for (int reg = 0; reg < 4; ++reg) {
                    const float mn = fmaxf(mrun[h][reg], mx[reg]);
                    const float alpha = __expf(mrun[h][reg] - mn);  // first chunk: exp(-inf)=0
                    mrun[h][reg] = mn;
                    lrun[h][reg] *= alpha;
                    #pragma unroll
                    for (int dt = 0; dt < 8; ++dt) oacc[h][dt][reg] *= alpha;
                }
            }
            #pragma unroll
            for (int reg = 0; reg < 4; ++reg) {
                float ls = 0.f;
                #pragma unroll
                for (int jt = 0; jt < 4; ++jt) {
                    const float pv = __expf(sc[h][jt][reg] - mrun[h][reg]);  // masked: 0
                    sc[h][jt][reg] = pv;
                    ls += pv;
                }
                lrun[h][reg] += rsum16(ls);
                #pragma unroll
                for (int jt = 0; jt < 4; ++jt)
                    Pl[w][h * 16 + quad * 4 + reg][jt * 16 + l15] = (__bf16)sc[h][jt][reg];
            }
        }
        // same-wave LDS write->read; compiler inserts the lgkmcnt wait

        // ---- O += P V: each V frag read once from L2, feeds both halves ----
        #pragma unroll
        for (int kj = 0; kj < 2; ++kj) {
            const bf16x8 pa0 = *(const bf16x8*)&Pl[w][l15][kj * 32 + quad * 8];
            const bf16x8 pa1 = *(const bf16x8*)&Pl[w][16 + l15][kj * 32 + quad * 8];
            #pragma unroll
            for (int dt = 0; dt < 8; ++dt) {
                const bf16x8 vf = *(const bf16x8*)&Vpb[off + (size_t)(kj * 8 + dt) * 512 + lane * 8];
                oacc[0][dt] = __builtin_amdgcn_mfma_f32_16x16x32_bf16(pa0, vf, oacc[0][dt], 0, 0, 0);
                oacc[1][dt] = __builtin_amdgcn_mfma_f32_16x16x32_bf16(pa1, vf, oacc[1][dt], 0, 0, 0);
            }
        }
    }

    // ---- merge the two waves' online-softmax partials (single barrier) ----
    if (w == 1) {
        #pragma unroll
        for (int h = 0; h < 2; ++h) {
            #pragma unroll
            for (int dt = 0; dt < 8; ++dt)
                *(f32x4*)&Olds[dt * 16 + l15][h * 16 + quad * 4] = oacc[h][dt];
            if (l15 == 0) {
                #pragma unroll
                for (int reg = 0; reg < 4; ++reg) {
                    Ml[h * 16 + quad * 4 + reg] = mrun[h][reg];
                    Ll[h * 16 + quad * 4 + reg] = lrun[h][reg];
                }
            }
        }
    }
    __syncthreads();
    if (w == 0) {
        #pragma unroll
        for (int h = 0; h < 2; ++h) {
            float a0[4], a1[4], linv[4];
            #pragma unroll
            for (int reg = 0; reg < 4; ++reg) {
                const int rr = h * 16 + quad * 4 + reg;
                const float m1 = Ml[rr];
                const float l1 = Ll[rr];
                const float m  = fmaxf(mrun[h][reg], m1);   // m0 always finite
                a0[reg] = __expf(mrun[h][reg] - m);
                a1[reg] = __expf(m1 - m);                   // wave1 empty: exp(-inf)=0
                linv[reg] = 1.0f / (lrun[h][reg] * a0[reg] + l1 * a1[reg]);
            }
            #pragma unroll
            for (int dt = 0; dt < 8; ++dt) {
                const f32x4 o1 = *(const f32x4*)&Olds[dt * 16 + l15][h * 16 + quad * 4];
                #pragma unroll
                for (int reg = 0; reg < 4; ++reg) {
                    const int gr = r0 + h * 16 + quad * 4 + reg;
                    const float v = (oacc[h][dt][reg] * a0[reg] + o1[reg] * a1[reg]) * linv[reg];
                    __builtin_nontemporal_store(v, out + ((size_t)b * Nc + gr) * Dc + dt * 16 + l15);
                }
            }
        }
    }
}

// ---- legacy fallback (in-kernel staging, 4 bias reads) for tiny ws ----
__global__ __launch_bounds__(256) void attn_mfma_legacy(
    const float* __restrict__ Q, const float* __restrict__ K, const float* __restrict__ V,
    const float* __restrict__ p0, const float* __restrict__ p1,
    const float* __restrict__ p2, const float* __restrict__ p3,
    const int* __restrict__ imask, const int* __restrict__ emask,
    float* __restrict__ out)
{
    __shared__ __align__(16) __bf16 Klds[64][136];
    __shared__ __align__(16) __bf16 Vt[128][72];
    __shared__ __align__(16) __bf16 Plds[4][16][72];
    const int tid  = threadIdx.x;
    const int w    = tid >> 6;
    const int lane = tid & 63;
    const int quad = lane >> 4;
    const int l15  = lane & 15;
    const int b = blockIdx.y;
    const int x = blockIdx.x, yy = blockIdx.y;
    const int ti = (yy < 8) ? x : (31 - x);
    const int q0 = ti * 64, q0w = q0 + w * 16;
    const float* Qb = Q + (size_t)b * Nc * Dc;
    const float* Kb = K + (size_t)b * Nc * Dc;
    const float* Vb = V + (size_t)b * Nc * Dc;
    const int* imb = imask + b * Nc;

    bf16x8 qfrag[4];
    {
        const int row = q0w + l15;
        const float qs = emask[b * Nc + row] ? SCALE_F : 0.0f;
        const float4* qr = (const float4*)(Qb + (size_t)row * Dc);
        #pragma unroll
        for (int kd = 0; kd < 4; ++kd) {
            const float4 xv = qr[kd * 8 + quad * 2];
            const float4 yv = qr[kd * 8 + quad * 2 + 1];
            qfrag[kd][0]=(__bf16)(xv.x*qs); qfrag[kd][1]=(__bf16)(xv.y*qs);
            qfrag[kd][2]=(__bf16)(xv.z*qs); qfrag[kd][3]=(__bf16)(xv.w*qs);
            qfrag[kd][4]=(__bf16)(yv.x*qs); qfrag[kd][5]=(__bf16)(yv.y*qs);
            qfrag[kd][6]=(__bf16)(yv.z*qs); qfrag[kd][7]=(__bf16)(yv.w*qs);
        }
    }
    f32x4 oacc[8];
    #pragma unroll
    for (int dt = 0; dt < 8; ++dt){oacc[dt][0]=0.f;oacc[dt][1]=0.f;oacc[dt][2]=0.f;oacc[dt][3]=0.f;}
    float mrun[4]={-INFINITY,-INFINITY,-INFINITY,-INFINITY}, lrun[4]={0.f,0.f,0.f,0.f};

    for (int m0 = 0; m0 <= q0; m0 += 64) {
        __syncthreads();
        #pragma unroll
        for (int it = 0; it < 8; ++it) {
            const int idx = it * 256 + tid;
            const int row = idx >> 5, c4 = idx & 31;
            const int gm = m0 + row;
            const float msk = imb[gm] ? 1.0f : 0.0f;
            const float4 kf = ((const float4*)(Kb + (size_t)gm * Dc))[c4];
            const float4 vf = ((const float4*)(Vb + (size_t)gm * Dc))[c4];
            bf16x4 kb;
            kb[0]=(__bf16)(kf.x*msk); kb[1]=(__bf16)(kf.y*msk);
            kb[2]=(__bf16)(kf.z*msk); kb[3]=(__bf16)(kf.w*msk);
            *(bf16x4*)&Klds[row][c4*4] = kb;
            Vt[c4*4+0][row]=(__bf16)(vf.x*msk); Vt[c4*4+1][row]=(__bf16)(vf.y*msk);
            Vt[c4*4+2][row]=(__bf16)(vf.z*msk); Vt[c4*4+3][row]=(__bf16)(vf.w*msk);
        }
        __syncthreads();
        f32x4 sc[4];
        #pragma unroll
        for (int jt = 0; jt < 4; ++jt){sc[jt][0]=0.f;sc[jt][1]=0.f;sc[jt][2]=0.f;sc[jt][3]=0.f;}
        #pragma unroll
        for (int jt = 0; jt < 4; ++jt)
            #pragma unroll
            for (int kd = 0; kd < 4; ++kd) {
                const bf16x8 bfr = *(const bf16x8*)&Klds[jt*16+l15][kd*32+quad*8];
                sc[jt] = __builtin_amdgcn_mfma_f32_16x16x32_bf16(qfrag[kd], bfr, sc[jt], 0, 0, 0);
            }
        #pragma unroll
        for (int jt = 0; jt < 4; ++jt)
            #pragma unroll
            for (int reg = 0; reg < 4; ++reg) {
                const int gr = q0w + quad*4 + reg;
                const int gc = m0 + jt*16 + l15;
                const size_t boff = (size_t)gr * Nc + gc;
                const float bsx = p0[boff] + p1[boff] + p2[boff] + p3[boff];
                const float v = sc[jt][reg] + bsx;
                sc[jt][reg] = (gc > gr) ? -INFINITY : v;
            }
        #pragma unroll
        for (int reg = 0; reg < 4; ++reg) {
            float mx = fmaxf(fmaxf(sc[0][reg], sc[1][reg]), fmaxf(sc[2][reg], sc[3][reg]));
            mx = rmax16(mx);
            const float mn = fmaxf(mrun[reg], mx);
            const float alpha = __expf(mrun[reg] - mn);
            mrun[reg] = mn; lrun[reg] *= alpha;
            #pragma unroll
            for (int dt = 0; dt < 8; ++dt) oacc[dt][reg] *= alpha;
            float ls = 0.f;
            #pragma unroll
            for (int jt = 0; jt < 4; ++jt) {
                const float pv = __expf(sc[jt][reg] - mn);
                sc[jt][reg] = pv; ls += pv;
            }
            lrun[reg] += rsum16(ls);
        }
        #pragma unroll
        for (int jt = 0; jt < 4; ++jt)
            #pragma unroll
            for (int reg = 0; reg < 4; ++reg)
                Plds[w][quad*4+reg][jt*16+l15] = (__bf16)sc[jt][reg];
        #pragma unroll
        for (int kj = 0; kj < 2; ++kj) {
            const bf16x8 pa = *(const bf16x8*)&Plds[w][l15][kj*32+quad*8];
            #pragma unroll
            for (int dt = 0; dt < 8; ++dt) {
                const bf16x8 vb = *(const bf16x8*)&Vt[dt*16+l15][kj*32+quad*8];
                oacc[dt] = __builtin_amdgcn_mfma_f32_16x16x32_bf16(pa, vb, oacc[dt], 0, 0, 0);
            }
        }
    }
    #pragma unroll
    for (int reg = 0; reg < 4; ++reg) {
        const float inv = 1.0f / lrun[reg];
        const int gr = q0w + quad*4 + reg;
        float* orow = out + ((size_t)b * Nc + gr) * Dc;
        #pragma unroll
        for (int dt = 0; dt < 8; ++dt)
            orow[dt*16+l15] = oacc[dt][reg] * inv;
    }
}

extern "C" void kernel_launch(void* const* d_in, const int* in_sizes, int n_in,
                              void* d_out, int out_size, void* d_ws, size_t ws_size,
                              hipStream_t stream) {
    const float* Q  = (const float*)d_in[0];
    const float* K  = (const float*)d_in[1];
    const float* V  = (const float*)d_in[2];
    const float* b0 = (const float*)d_in[3];
    const float* b1 = (const float*)d_in[4];
    const float* b2 = (const float*)d_in[5];
    const float* b3 = (const float*)d_in[6];
    const int* im   = (const int*)d_in[7];
    const int* em   = (const int*)d_in[8];
    float* out      = (float*)d_out;

    if (ws_size >= KPACK_BYTES + VPACK_BYTES + BIAS_BYTES) {
        __bf16* Kp = (__bf16*)d_ws;
        __bf16* Vp = (__bf16*)((char*)d_ws + KPACK_BYTES);
        float*  bs = (float*)((char*)d_ws + KPACK_BYTES + VPACK_BYTES);
        prep_fused<<<512 + (Nc * Nc / 4) / 256, 256, 0, stream>>>(
            K, V, im, b0, b1, b2, b3, Kp, Vp, bs);
        attn_wave<<<dim3(Bc, 64), 128, 0, stream>>>(Q, Kp, Vp, bs, em, out);
    } else {
        attn_mfma_legacy<<<dim3(NCHUNK, Bc), 256, 0, stream>>>(
            Q, K, V, b0, b1, b2, b3, im, em, out);
    }
}

// Round 3
// 246.674 us; speedup vs baseline: 1.0061x; 1.0061x over previous
//
#include <hip/hip_runtime.h>
#include <math.h>

// (B, N, D) = (16, 2048, 128)
constexpr int Bc = 16;
constexpr int Nc = 2048;
constexpr int Dc = 128;
constexpr int NCHUNK = Nc / 64;          // 32 key-chunks of 64
constexpr float SCALE_F = 0.08838834764831845f;  // 1/sqrt(128)

typedef __bf16 bf16x8 __attribute__((ext_vector_type(8)));
typedef __bf16 bf16x4 __attribute__((ext_vector_type(4)));
typedef float  f32x4  __attribute__((ext_vector_type(4)));

// ws layout: Kpack 8MB | Vpack 8MB | bias_packed 8.65MB (causal, fragment order)
constexpr size_t KPACK_BYTES = (size_t)Bc * NCHUNK * 16 * 64 * 16;
constexpr size_t VPACK_BYTES = KPACK_BYTES;
constexpr int NUNITS = 1056;             // sum_t C(t), C(t) = t/2+1, t in [0,64)
constexpr size_t BIASP_BYTES = (size_t)NUNITS * 2048 * 4;
constexpr int CHUNK_ELEMS = 16 * 64 * 8;  // 8192 bf16 = 16KB per chunk

// prefix of causal chunk counts: f(t) = sum_{t'<t} (t'/2+1)
__device__ __forceinline__ int ftri(int t) {
    const int m = t >> 1;
    return (t & 1) ? (m + 1) * (m + 1) : m * (m + 1);
}

// ---- DPP 16-lane row reductions (VALU pipe, no LDS/lgkm) ----
template<int CTRL>
__device__ __forceinline__ float dpp_mv(float v) {
    return __builtin_bit_cast(float,
        __builtin_amdgcn_update_dpp(0, __builtin_bit_cast(int, v),
                                    CTRL, 0xF, 0xF, true));
}
__device__ __forceinline__ float rmax16(float v) {
    v = fmaxf(v, dpp_mv<0xB1>(v));
    v = fmaxf(v, dpp_mv<0x4E>(v));
    v = fmaxf(v, dpp_mv<0x141>(v));
    v = fmaxf(v, dpp_mv<0x140>(v));
    return v;
}
__device__ __forceinline__ float rsum16(float v) {
    v += dpp_mv<0xB1>(v);
    v += dpp_mv<0x4E>(v);
    v += dpp_mv<0x141>(v);
    v += dpp_mv<0x140>(v);
    return v;
}

// ---- fused prep ----
// blocks [0,512): pack K/V into MFMA fragment chunks.
// blocks [512,512+1056): sum 4 biases for one (t,c) causal 32x64 tile and
//   write it in the exact per-lane fragment order attn consumes
//   (8 coalesced f32x4 loads per lane per chunk instead of 32 scattered dwords).
__global__ __launch_bounds__(256) void prep_fused(
    const float* __restrict__ K, const float* __restrict__ V,
    const int* __restrict__ imask,
    const float* __restrict__ b0, const float* __restrict__ b1,
    const float* __restrict__ b2, const float* __restrict__ b3,
    __bf16* __restrict__ Kp, __bf16* __restrict__ Vp, float* __restrict__ bsp)
{
    __shared__ __align__(16) __bf16 Ks[64][136];
    __shared__ __align__(16) __bf16 Vs[64][136];
    __shared__ __align__(16) float  Ts[32][68];
    const int bid = blockIdx.x;
    const int tid = threadIdx.x;

    if (bid >= 512) {
        const int u = bid - 512;               // unit in [0,1056)
        int t = 0;
        while (ftri(t + 1) <= u) ++t;          // <=64 scalar iters, once per block
        const int c = u - ftri(t);

        #pragma unroll
        for (int i = 0; i < 2; ++i) {
            const int v = tid + 256 * i;
            const int row = v >> 4, c4 = v & 15;
            const size_t g = (size_t)(t * 32 + row) * Nc + c * 64 + c4 * 4;
            const float4 a = *(const float4*)(b0 + g);
            const float4 d = *(const float4*)(b1 + g);
            const float4 e = *(const float4*)(b2 + g);
            const float4 f = *(const float4*)(b3 + g);
            float4 s;
            s.x = a.x + d.x + e.x + f.x;
            s.y = a.y + d.y + e.y + f.y;
            s.z = a.z + d.z + e.z + f.z;
            s.w = a.w + d.w + e.w + f.w;
            *(float4*)&Ts[row][c4 * 4] = s;
        }
        __syncthreads();

        const int lane = tid >> 2;
        const int quad = lane >> 4, l15 = lane & 15;
        const int k0 = (tid & 3) * 8;
        float* outp = bsp + (size_t)u * 2048;
        #pragma unroll
        for (int g2 = 0; g2 < 2; ++g2) {
            const int k = k0 + g2 * 4;
            const int h = (k >> 4) & 1, jt = (k >> 2) & 3;
            float4 o;
            o.x = Ts[h * 16 + quad * 4 + 0][jt * 16 + l15];
            o.y = Ts[h * 16 + quad * 4 + 1][jt * 16 + l15];
            o.z = Ts[h * 16 + quad * 4 + 2][jt * 16 + l15];
            o.w = Ts[h * 16 + quad * 4 + 3][jt * 16 + l15];
            ((float4*)outp)[tid * 2 + g2] = o;
        }
        return;
    }

    const int c = bid & 31;
    const int b = bid >> 5;
    const int m0 = c * 64;
    const float* Kb = K + (size_t)b * Nc * Dc;
    const float* Vb = V + (size_t)b * Nc * Dc;
    const int* imb = imask + b * Nc;

    #pragma unroll
    for (int it = 0; it < 8; ++it) {
        const int idx = it * 256 + tid;
        const int row = idx >> 5;
        const int c4  = idx & 31;
        const int gm  = m0 + row;
        const float msk = imb[gm] ? 1.0f : 0.0f;
        const float4 kf = ((const float4*)(Kb + (size_t)gm * Dc))[c4];
        const float4 vf = ((const float4*)(Vb + (size_t)gm * Dc))[c4];
        bf16x4 kb, vb;
        kb[0] = (__bf16)(kf.x * msk); kb[1] = (__bf16)(kf.y * msk);
        kb[2] = (__bf16)(kf.z * msk); kb[3] = (__bf16)(kf.w * msk);
        vb[0] = (__bf16)(vf.x * msk); vb[1] = (__bf16)(vf.y * msk);
        vb[2] = (__bf16)(vf.z * msk); vb[3] = (__bf16)(vf.w * msk);
        *(bf16x4*)&Ks[row][c4 * 4] = kb;
        *(bf16x4*)&Vs[row][c4 * 4] = vb;
    }
    __syncthreads();

    const size_t chunk_base = (size_t)(b * NCHUNK + c) * CHUNK_ELEMS;
    #pragma unroll
    for (int i = 0; i < 4; ++i) {
        const int s = i * 256 + tid;
        const int f = s >> 6;
        const int l = s & 63;
        const int quad = (l >> 4) & 3;
        const int l15  = l & 15;
        {   // K frag f=jt*4+kd
            const int jt = f >> 2, kd = f & 3;
            const bf16x8 kv = *(const bf16x8*)&Ks[jt * 16 + l15][kd * 32 + quad * 8];
            *(bf16x8*)&Kp[chunk_base + (size_t)f * 512 + l * 8] = kv;
        }
        {   // V frag f=kj*8+dt
            const int kj = f >> 3, dt = f & 7;
            bf16x8 vv;
            #pragma unroll
            for (int j = 0; j < 8; ++j)
                vv[j] = Vs[kj * 32 + quad * 8 + j][dt * 16 + l15];
            *(bf16x8*)&Vp[chunk_base + (size_t)f * 512 + l * 8] = vv;
        }
    }
}

// ---- main: chunk-split flash attention, 4 waves per 32-row tile ----
// grid (b=16, y=64), 256 threads = 4 waves; wave w takes chunks c===w (mod 4).
//  - longest serial chain: 8 chunks (was 16); all 4 waves of a block stay
//    live until the 3-barrier merge -> 12-16 waves/CU resident through the
//    tail (vs ~1/SIMD drained before).
//  - merge chain ordered w3->w2->w1->w0 so the last-finishing wave (w0 has
//    the extra chunk when C%4!=0) does the final merge: chain hides under it.
//  - packed bias doubles as the MFMA C-initializer (exact same fragment
//    layout) -> no separate bias-add pass, bq regs alias into sc (fits the
//    170-VGPR cap of 3 waves/SIMD without spills).
__global__ __launch_bounds__(256, 3) void attn_split(
    const float* __restrict__ Q,
    const __bf16* __restrict__ Kp, const __bf16* __restrict__ Vp,
    const float* __restrict__ biasp, const int* __restrict__ emask,
    float* __restrict__ out)
{
    __shared__ __align__(16) __bf16 Pl[4][32][72];   // per-wave P transpose
    __shared__ __align__(16) float  Olds[128][36];   // merge buffer
    __shared__ float Ml[32];
    __shared__ float Ll[32];

    const int tid  = threadIdx.x;
    const int w    = tid >> 6;
    const int lane = tid & 63;
    const int quad = lane >> 4;
    const int l15  = lane & 15;
    const int b = blockIdx.x;
    const int y = blockIdx.y;
    // co-resident CU set {y, y+16, y+32, y+48} (ids differ by 256); this
    // permutation makes their chunk-counts sum to 66 for every y.
    const int t = (y < 32) ? y : ((y < 48) ? (79 - y) : (111 - y));
    const int r0 = t * 32;                 // tile rows [r0, r0+32)
    const int C  = (t >> 1) + 1;           // causal key-chunk count
    const int mh = t >> 1;
    const int fbase = (t & 1) ? (mh + 1) * (mh + 1) : mh * (mh + 1);  // ftri(t)

    const float*  Qb  = Q  + (size_t)b * Nc * Dc;
    const __bf16* Kpb = Kp + (size_t)b * NCHUNK * CHUNK_ELEMS;
    const __bf16* Vpb = Vp + (size_t)b * NCHUNK * CHUNK_ELEMS;

    // ---- Q fragments for both 16-row halves (emask + SCALE folded) ----
    bf16x8 qf[2][4];
    #pragma unroll
    for (int h = 0; h < 2; ++h) {
        const int row = r0 + h * 16 + l15;
        const float qs = emask[b * Nc + row] ? SCALE_F : 0.0f;
        const float4* qr = (const float4*)(Qb + (size_t)row * Dc);
        #pragma unroll
        for (int kd = 0; kd < 4; ++kd) {
            const float4 xx = qr[kd * 8 + quad * 2];
            const float4 yy = qr[kd * 8 + quad * 2 + 1];
            qf[h][kd][0] = (__bf16)(xx.x * qs); qf[h][kd][1] = (__bf16)(xx.y * qs);
            qf[h][kd][2] = (__bf16)(xx.z * qs); qf[h][kd][3] = (__bf16)(xx.w * qs);
            qf[h][kd][4] = (__bf16)(yy.x * qs); qf[h][kd][5] = (__bf16)(yy.y * qs);
            qf[h][kd][6] = (__bf16)(yy.z * qs); qf[h][kd][7] = (__bf16)(yy.w * qs);
        }
    }

    f32x4 oacc[2][8];
    float mrun[2][4], lrun[2][4];
    #pragma unroll
    for (int h = 0; h < 2; ++h) {
        #pragma unroll
        for (int dt = 0; dt < 8; ++dt) {
            oacc[h][dt][0] = 0.f; oacc[h][dt][1] = 0.f;
            oacc[h][dt][2] = 0.f; oacc[h][dt][3] = 0.f;
        }
        #pragma unroll
        for (int reg = 0; reg < 4; ++reg) { mrun[h][reg] = -INFINITY; lrun[h][reg] = 0.f; }
    }

    for (int c = w; c < C; c += 4) {
        const __bf16* kc = Kpb + (size_t)c * CHUNK_ELEMS;
        const __bf16* vc = Vpb + (size_t)c * CHUNK_ELEMS;
        const f32x4* bpp = (const f32x4*)(biasp + (size_t)(fbase + c) * 2048) + lane * 8;

        // ---- QK with bias as the C-initializer (packed in acc layout) ----
        f32x4 sc[2][4];
        #pragma unroll
        for (int h = 0; h < 2; ++h)
            #pragma unroll
            for (int jt = 0; jt < 4; ++jt)
                sc[h][jt] = bpp[h * 4 + jt];
        #pragma unroll
        for (int jt = 0; jt < 4; ++jt)
            #pragma unroll
            for (int kd = 0; kd < 4; ++kd) {
                const bf16x8 kf = *(const bf16x8*)&kc[(size_t)(jt * 4 + kd) * 512 + lane * 8];
                sc[0][jt] = __builtin_amdgcn_mfma_f32_16x16x32_bf16(qf[0][kd], kf, sc[0][jt], 0, 0, 0);
                sc[1][jt] = __builtin_amdgcn_mfma_f32_16x16x32_bf16(qf[1][kd], kf, sc[1][jt], 0, 0, 0);
            }

        // ---- causal mask on the diagonal chunk (bias already included) ----
        if (c == C - 1) {
            #pragma unroll
            for (int h = 0; h < 2; ++h)
                #pragma unroll
                for (int jt = 0; jt < 4; ++jt)
                    #pragma unroll
                    for (int reg = 0; reg < 4; ++reg) {
                        const int gr = r0 + h * 16 + quad * 4 + reg;
                        const int gc = c * 64 + jt * 16 + l15;
                        if (gc > gr) sc[h][jt][reg] = -INFINITY;
                    }
        }

        // ---- online softmax per half; exact rescale-skip when no growth ----
        #pragma unroll
        for (int h = 0; h < 2; ++h) {
            float mx[4];
            int grow = 0;
            #pragma unroll
            for (int reg = 0; reg < 4; ++reg) {
                float m = fmaxf(fmaxf(sc[h][0][reg], sc[h][1][reg]),
                                fmaxf(sc[h][2][reg], sc[h][3][reg]));
                m = rmax16(m);
                mx[reg] = m;
                grow |= (m > mrun[h][reg]);
            }
            if (__any(grow)) {   // wave-uniform; skip path is numerically exact
                #pragma unroll
                for (int reg = 0; reg < 4; ++reg) {
                    const float mn = fmaxf(mrun[h][reg], mx[reg]);
                    const float alpha = __expf(mrun[h][reg] - mn);  // first chunk: exp(-inf)=0
                    mrun[h][reg] = mn;
                    lrun[h][reg] *= alpha;
                    #pragma unroll
                    for (int dt = 0; dt < 8; ++dt) oacc[h][dt][reg] *= alpha;
                }
            }
            #pragma unroll
            for (int reg = 0; reg < 4; ++reg) {
                float ls = 0.f;
                #pragma unroll
                for (int jt = 0; jt < 4; ++jt) {
                    const float pv = __expf(sc[h][jt][reg] - mrun[h][reg]);  // masked: 0
                    sc[h][jt][reg] = pv;
                    ls += pv;
                }
                lrun[h][reg] += rsum16(ls);
                #pragma unroll
                for (int jt = 0; jt < 4; ++jt)
                    Pl[w][h * 16 + quad * 4 + reg][jt * 16 + l15] = (__bf16)sc[h][jt][reg];
            }
        }
        // same-wave LDS write->read; compiler inserts the lgkmcnt wait

        // ---- O += P V: each V frag read once from L2, feeds both halves ----
        #pragma unroll
        for (int kj = 0; kj < 2; ++kj) {
            const bf16x8 pa0 = *(const bf16x8*)&Pl[w][l15][kj * 32 + quad * 8];
            const bf16x8 pa1 = *(const bf16x8*)&Pl[w][16 + l15][kj * 32 + quad * 8];
            #pragma unroll
            for (int dt = 0; dt < 8; ++dt) {
                const bf16x8 vf = *(const bf16x8*)&vc[(size_t)(kj * 8 + dt) * 512 + lane * 8];
                oacc[0][dt] = __builtin_amdgcn_mfma_f32_16x16x32_bf16(pa0, vf, oacc[0][dt], 0, 0, 0);
                oacc[1][dt] = __builtin_amdgcn_mfma_f32_16x16x32_bf16(pa1, vf, oacc[1][dt], 0, 0, 0);
            }
        }
    }

    // ---- sequential merge chain w3 -> w2 -> w1 -> w0 (3 barriers) ----
    auto write_partial = [&]() {
        #pragma unroll
        for (int h = 0; h < 2; ++h) {
            #pragma unroll
            for (int dt = 0; dt < 8; ++dt)
                *(f32x4*)&Olds[dt * 16 + l15][h * 16 + quad * 4] = oacc[h][dt];
            if (l15 == 0) {
                #pragma unroll
                for (int reg = 0; reg < 4; ++reg) {
                    Ml[h * 16 + quad * 4 + reg] = mrun[h][reg];
                    Ll[h * 16 + quad * 4 + reg] = lrun[h][reg];
                }
            }
        }
    };
    auto merge_lds = [&]() {
        #pragma unroll
        for (int h = 0; h < 2; ++h) {
            float aw[4], al[4];
            #pragma unroll
            for (int reg = 0; reg < 4; ++reg) {
                const int rr = h * 16 + quad * 4 + reg;
                const float mL = Ml[rr], lL = Ll[rr];
                const float m = fmaxf(mrun[h][reg], mL);
                const float mm = (m == -INFINITY) ? 0.0f : m;  // both-empty guard
                aw[reg] = __expf(mrun[h][reg] - mm);
                al[reg] = __expf(mL - mm);
                mrun[h][reg] = m;
                lrun[h][reg] = lrun[h][reg] * aw[reg] + lL * al[reg];
            }
            #pragma unroll
            for (int dt = 0; dt < 8; ++dt) {
                const f32x4 o = *(const f32x4*)&Olds[dt * 16 + l15][h * 16 + quad * 4];
                #pragma unroll
                for (int reg = 0; reg < 4; ++reg)
                    oacc[h][dt][reg] = oacc[h][dt][reg] * aw[reg] + o[reg] * al[reg];
            }
        }
    };

    if (w == 3) write_partial();
    __syncthreads();
    if (w == 2) { merge_lds(); write_partial(); }
    __syncthreads();
    if (w == 1) { merge_lds(); write_partial(); }
    __syncthreads();
    if (w == 0) {
        merge_lds();
        #pragma unroll
        for (int h = 0; h < 2; ++h) {
            #pragma unroll
            for (int reg = 0; reg < 4; ++reg) {
                const float inv = 1.0f / lrun[h][reg];
                const int gr = r0 + h * 16 + quad * 4 + reg;
                float* orow = out + ((size_t)b * Nc + gr) * Dc;
                #pragma unroll
                for (int dt = 0; dt < 8; ++dt)
                    __builtin_nontemporal_store(oacc[h][dt][reg] * inv, orow + dt * 16 + l15);
            }
        }
    }
}

// ---- legacy fallback (in-kernel staging, 4 bias reads) for tiny ws ----
__global__ __launch_bounds__(256) void attn_mfma_legacy(
    const float* __restrict__ Q, const float* __restrict__ K, const float* __restrict__ V,
    const float* __restrict__ p0, const float* __restrict__ p1,
    const float* __restrict__ p2, const float* __restrict__ p3,
    const int* __restrict__ imask, const int* __restrict__ emask,
    float* __restrict__ out)
{
    __shared__ __align__(16) __bf16 Klds[64][136];
    __shared__ __align__(16) __bf16 Vt[128][72];
    __shared__ __align__(16) __bf16 Plds[4][16][72];
    const int tid  = threadIdx.x;
    const int w    = tid >> 6;
    const int lane = tid & 63;
    const int quad = lane >> 4;
    const int l15  = lane & 15;
    const int b = blockIdx.y;
    const int x = blockIdx.x, yy = blockIdx.y;
    const int ti = (yy < 8) ? x : (31 - x);
    const int q0 = ti * 64, q0w = q0 + w * 16;
    const float* Qb = Q + (size_t)b * Nc * Dc;
    const float* Kb = K + (size_t)b * Nc * Dc;
    const float* Vb = V + (size_t)b * Nc * Dc;
    const int* imb = imask + b * Nc;

    bf16x8 qfrag[4];
    {
        const int row = q0w + l15;
        const float qs = emask[b * Nc + row] ? SCALE_F : 0.0f;
        const float4* qr = (const float4*)(Qb + (size_t)row * Dc);
        #pragma unroll
        for (int kd = 0; kd < 4; ++kd) {
            const float4 xv = qr[kd * 8 + quad * 2];
            const float4 yv = qr[kd * 8 + quad * 2 + 1];
            qfrag[kd][0]=(__bf16)(xv.x*qs); qfrag[kd][1]=(__bf16)(xv.y*qs);
            qfrag[kd][2]=(__bf16)(xv.z*qs); qfrag[kd][3]=(__bf16)(xv.w*qs);
            qfrag[kd][4]=(__bf16)(yv.x*qs); qfrag[kd][5]=(__bf16)(yv.y*qs);
            qfrag[kd][6]=(__bf16)(yv.z*qs); qfrag[kd][7]=(__bf16)(yv.w*qs);
        }
    }
    f32x4 oacc[8];
    #pragma unroll
    for (int dt = 0; dt < 8; ++dt){oacc[dt][0]=0.f;oacc[dt][1]=0.f;oacc[dt][2]=0.f;oacc[dt][3]=0.f;}
    float mrun[4]={-INFINITY,-INFINITY,-INFINITY,-INFINITY}, lrun[4]={0.f,0.f,0.f,0.f};

    for (int m0 = 0; m0 <= q0; m0 += 64) {
        __syncthreads();
        #pragma unroll
        for (int it = 0; it < 8; ++it) {
            const int idx = it * 256 + tid;
            const int row = idx >> 5, c4 = idx & 31;
            const int gm = m0 + row;
            const float msk = imb[gm] ? 1.0f : 0.0f;
            const float4 kf = ((const float4*)(Kb + (size_t)gm * Dc))[c4];
            const float4 vf = ((const float4*)(Vb + (size_t)gm * Dc))[c4];
            bf16x4 kb;
            kb[0]=(__bf16)(kf.x*msk); kb[1]=(__bf16)(kf.y*msk);
            kb[2]=(__bf16)(kf.z*msk); kb[3]=(__bf16)(kf.w*msk);
            *(bf16x4*)&Klds[row][c4*4] = kb;
            Vt[c4*4+0][row]=(__bf16)(vf.x*msk); Vt[c4*4+1][row]=(__bf16)(vf.y*msk);
            Vt[c4*4+2][row]=(__bf16)(vf.z*msk); Vt[c4*4+3][row]=(__bf16)(vf.w*msk);
        }
        __syncthreads();
        f32x4 sc[4];
        #pragma unroll
        for (int jt = 0; jt < 4; ++jt){sc[jt][0]=0.f;sc[jt][1]=0.f;sc[jt][2]=0.f;sc[jt][3]=0.f;}
        #pragma unroll
        for (int jt = 0; jt < 4; ++jt)
            #pragma unroll
            for (int kd = 0; kd < 4; ++kd) {
                const bf16x8 bfr = *(const bf16x8*)&Klds[jt*16+l15][kd*32+quad*8];
                sc[jt] = __builtin_amdgcn_mfma_f32_16x16x32_bf16(qfrag[kd], bfr, sc[jt], 0, 0, 0);
            }
        #pragma unroll
        for (int jt = 0; jt < 4; ++jt)
            #pragma unroll
            for (int reg = 0; reg < 4; ++reg) {
                const int gr = q0w + quad*4 + reg;
                const int gc = m0 + jt*16 + l15;
                const size_t boff = (size_t)gr * Nc + gc;
                const float bsx = p0[boff] + p1[boff] + p2[boff] + p3[boff];
                const float v = sc[jt][reg] + bsx;
                sc[jt][reg] = (gc > gr) ? -INFINITY : v;
            }
        #pragma unroll
        for (int reg = 0; reg < 4; ++reg) {
            float mx = fmaxf(fmaxf(sc[0][reg], sc[1][reg]), fmaxf(sc[2][reg], sc[3][reg]));
            mx = rmax16(mx);
            const float mn = fmaxf(mrun[reg], mx);
            const float alpha = __expf(mrun[reg] - mn);
            mrun[reg] = mn; lrun[reg] *= alpha;
            #pragma unroll
            for (int dt = 0; dt < 8; ++dt) oacc[dt][reg] *= alpha;
            float ls = 0.f;
            #pragma unroll
            for (int jt = 0; jt < 4; ++jt) {
                const float pv = __expf(sc[jt][reg] - mn);
                sc[jt][reg] = pv; ls += pv;
            }
            lrun[reg] += rsum16(ls);
        }
        #pragma unroll
        for (int jt = 0; jt < 4; ++jt)
            #pragma unroll
            for (int reg = 0; reg < 4; ++reg)
                Plds[w][quad*4+reg][jt*16+l15] = (__bf16)sc[jt][reg];
        #pragma unroll
        for (int kj = 0; kj < 2; ++kj) {
            const bf16x8 pa = *(const bf16x8*)&Plds[w][l15][kj*32+quad*8];
            #pragma unroll
            for (int dt = 0; dt < 8; ++dt) {
                const bf16x8 vb = *(const bf16x8*)&Vt[dt*16+l15][kj*32+quad*8];
                oacc[dt] = __builtin_amdgcn_mfma_f32_16x16x32_bf16(pa, vb, oacc[dt], 0, 0, 0);
            }
        }
    }
    #pragma unroll
    for (int reg = 0; reg < 4; ++reg) {
        const float inv = 1.0f / lrun[reg];
        const int gr = q0w + quad*4 + reg;
        float* orow = out + ((size_t)b * Nc + gr) * Dc;
        #pragma unroll
        for (int dt = 0; dt < 8; ++dt)
            orow[dt*16+l15] = oacc[dt][reg] * inv;
    }
}

extern "C" void kernel_launch(void* const* d_in, const int* in_sizes, int n_in,
                              void* d_out, int out_size, void* d_ws, size_t ws_size,
                              hipStream_t stream) {
    const float* Q  = (const float*)d_in[0];
    const float* K  = (const float*)d_in[1];
    const float* V  = (const float*)d_in[2];
    const float* b0 = (const float*)d_in[3];
    const float* b1 = (const float*)d_in[4];
    const float* b2 = (const float*)d_in[5];
    const float* b3 = (const float*)d_in[6];
    const int* im   = (const int*)d_in[7];
    const int* em   = (const int*)d_in[8];
    float* out      = (float*)d_out;

    if (ws_size >= KPACK_BYTES + VPACK_BYTES + BIASP_BYTES) {
        __bf16* Kp  = (__bf16*)d_ws;
        __bf16* Vp  = (__bf16*)((char*)d_ws + KPACK_BYTES);
        float*  bsp = (float*)((char*)d_ws + KPACK_BYTES + VPACK_BYTES);
        prep_fused<<<512 + NUNITS, 256, 0, stream>>>(
            K, V, im, b0, b1, b2, b3, Kp, Vp, bsp);
        attn_split<<<dim3(Bc, 64), 256, 0, stream>>>(Q, Kp, Vp, bsp, em, out);
    } else {
        attn_mfma_legacy<<<dim3(NCHUNK, Bc), 256, 0, stream>>>(
            Q, K, V, b0, b1, b2, b3, im, em, out);
    }
}

// Round 4
// 240.267 us; speedup vs baseline: 1.0329x; 1.0267x over previous
//
#include <hip/hip_runtime.h>
#include <math.h>

// (B, N, D) = (16, 2048, 128)
constexpr int Bc = 16;
constexpr int Nc = 2048;
constexpr int Dc = 128;
constexpr int NCHUNK = Nc / 64;          // 32 key-chunks of 64
constexpr float SCALE_F = 0.08838834764831845f;  // 1/sqrt(128)

typedef __bf16 bf16x8 __attribute__((ext_vector_type(8)));
typedef __bf16 bf16x4 __attribute__((ext_vector_type(4)));
typedef float  f32x4  __attribute__((ext_vector_type(4)));

// ws layout: Kpack 8MB | Vpack 8MB | bias_packed 8.65MB | partials 38.3MB
constexpr size_t KPACK_BYTES = (size_t)Bc * NCHUNK * 16 * 64 * 16;
constexpr size_t VPACK_BYTES = KPACK_BYTES;
constexpr int NUNITS = 1056;             // sum_t C(t), C(t)=t/2+1, t in [0,64)
constexpr size_t BIASP_BYTES = (size_t)NUNITS * 2048 * 4;
constexpr int CHUNK_ELEMS = 16 * 64 * 8; // 8192 bf16 = 16KB per chunk
// split-C partials: 72 sliced units per b (tiles t=8..31), each 64x128 O + m[64] + l[64]
constexpr int PART_FLOATS = 64 * 128 + 64 + 64;   // 8320
constexpr size_t PART_BYTES = (size_t)Bc * 72 * PART_FLOATS * 4;

// prefix of causal chunk counts over 32-row tiles: ftri(t)=sum_{t'<t}(t'/2+1)
__device__ __forceinline__ int ftri(int t) {
    const int m = t >> 1;
    return (t & 1) ? (m + 1) * (m + 1) : m * (m + 1);
}

__device__ __forceinline__ void gload_lds16(const __bf16* gsrc, __bf16* ldst) {
    // 16B per lane; LDS dest = wave-uniform base + lane*16 (HW rule).
    __builtin_amdgcn_global_load_lds(
        (const __attribute__((address_space(1))) unsigned int*)gsrc,
        (__attribute__((address_space(3))) unsigned int*)ldst, 16, 0, 0);
}

// ---- DPP 16-lane row reductions (VALU pipe, no LDS/lgkm) ----
template<int CTRL>
__device__ __forceinline__ float dpp_mv(float v) {
    return __builtin_bit_cast(float,
        __builtin_amdgcn_update_dpp(0, __builtin_bit_cast(int, v),
                                    CTRL, 0xF, 0xF, true));
}
__device__ __forceinline__ float rmax16(float v) {
    v = fmaxf(v, dpp_mv<0xB1>(v));
    v = fmaxf(v, dpp_mv<0x4E>(v));
    v = fmaxf(v, dpp_mv<0x141>(v));
    v = fmaxf(v, dpp_mv<0x140>(v));
    return v;
}
__device__ __forceinline__ float rsum16(float v) {
    v += dpp_mv<0xB1>(v);
    v += dpp_mv<0x4E>(v);
    v += dpp_mv<0x141>(v);
    v += dpp_mv<0x140>(v);
    return v;
}

// ---- fused prep (verbatim from R3 — correctness-proven) ----
// blocks [0,512): pack K/V into MFMA fragment chunks.
// blocks [512,512+1056): sum 4 biases for one (t32,c) causal 32x64 tile,
//   written in the exact per-lane fragment order attn consumes.
__global__ __launch_bounds__(256) void prep_fused(
    const float* __restrict__ K, const float* __restrict__ V,
    const int* __restrict__ imask,
    const float* __restrict__ b0, const float* __restrict__ b1,
    const float* __restrict__ b2, const float* __restrict__ b3,
    __bf16* __restrict__ Kp, __bf16* __restrict__ Vp, float* __restrict__ bsp)
{
    __shared__ __align__(16) __bf16 Ks[64][136];
    __shared__ __align__(16) __bf16 Vs[64][136];
    __shared__ __align__(16) float  Ts[32][68];
    const int bid = blockIdx.x;
    const int tid = threadIdx.x;

    if (bid >= 512) {
        const int u = bid - 512;               // unit in [0,1056)
        int t = 0;
        while (ftri(t + 1) <= u) ++t;          // <=64 scalar iters, once per block
        const int c = u - ftri(t);

        #pragma unroll
        for (int i = 0; i < 2; ++i) {
            const int v = tid + 256 * i;
            const int row = v >> 4, c4 = v & 15;
            const size_t g = (size_t)(t * 32 + row) * Nc + c * 64 + c4 * 4;
            const float4 a = *(const float4*)(b0 + g);
            const float4 d = *(const float4*)(b1 + g);
            const float4 e = *(const float4*)(b2 + g);
            const float4 f = *(const float4*)(b3 + g);
            float4 s;
            s.x = a.x + d.x + e.x + f.x;
            s.y = a.y + d.y + e.y + f.y;
            s.z = a.z + d.z + e.z + f.z;
            s.w = a.w + d.w + e.w + f.w;
            *(float4*)&Ts[row][c4 * 4] = s;
        }
        __syncthreads();

        const int lane = tid >> 2;
        const int quad = lane >> 4, l15 = lane & 15;
        const int k0 = (tid & 3) * 8;
        float* outp = bsp + (size_t)u * 2048;
        #pragma unroll
        for (int g2 = 0; g2 < 2; ++g2) {
            const int k = k0 + g2 * 4;
            const int h = (k >> 4) & 1, jt = (k >> 2) & 3;
            float4 o;
            o.x = Ts[h * 16 + quad * 4 + 0][jt * 16 + l15];
            o.y = Ts[h * 16 + quad * 4 + 1][jt * 16 + l15];
            o.z = Ts[h * 16 + quad * 4 + 2][jt * 16 + l15];
            o.w = Ts[h * 16 + quad * 4 + 3][jt * 16 + l15];
            ((float4*)outp)[tid * 2 + g2] = o;
        }
        return;
    }

    const int c = bid & 31;
    const int b = bid >> 5;
    const int m0 = c * 64;
    const float* Kb = K + (size_t)b * Nc * Dc;
    const float* Vb = V + (size_t)b * Nc * Dc;
    const int* imb = imask + b * Nc;

    #pragma unroll
    for (int it = 0; it < 8; ++it) {
        const int idx = it * 256 + tid;
        const int row = idx >> 5;
        const int c4  = idx & 31;
        const int gm  = m0 + row;
        const float msk = imb[gm] ? 1.0f : 0.0f;
        const float4 kf = ((const float4*)(Kb + (size_t)gm * Dc))[c4];
        const float4 vf = ((const float4*)(Vb + (size_t)gm * Dc))[c4];
        bf16x4 kb, vb;
        kb[0] = (__bf16)(kf.x * msk); kb[1] = (__bf16)(kf.y * msk);
        kb[2] = (__bf16)(kf.z * msk); kb[3] = (__bf16)(kf.w * msk);
        vb[0] = (__bf16)(vf.x * msk); vb[1] = (__bf16)(vf.y * msk);
        vb[2] = (__bf16)(vf.z * msk); vb[3] = (__bf16)(vf.w * msk);
        *(bf16x4*)&Ks[row][c4 * 4] = kb;
        *(bf16x4*)&Vs[row][c4 * 4] = vb;
    }
    __syncthreads();

    const size_t chunk_base = (size_t)(b * NCHUNK + c) * CHUNK_ELEMS;
    #pragma unroll
    for (int i = 0; i < 4; ++i) {
        const int s = i * 256 + tid;
        const int f = s >> 6;
        const int l = s & 63;
        const int quad = (l >> 4) & 3;
        const int l15  = l & 15;
        {   // K frag f=jt*4+kd
            const int jt = f >> 2, kd = f & 3;
            const bf16x8 kv = *(const bf16x8*)&Ks[jt * 16 + l15][kd * 32 + quad * 8];
            *(bf16x8*)&Kp[chunk_base + (size_t)f * 512 + l * 8] = kv;
        }
        {   // V frag f=kj*8+dt
            const int kj = f >> 3, dt = f & 7;
            bf16x8 vv;
            #pragma unroll
            for (int j = 0; j < 8; ++j)
                vv[j] = Vs[kj * 32 + quad * 8 + j][dt * 16 + l15];
            *(bf16x8*)&Vp[chunk_base + (size_t)f * 512 + l * 8] = vv;
        }
    }
}

// ---- main: R0's pipelined MFMA flash attention + split-C + packed bias ----
// SPLIT: grid (16, 80); unit u = 79-y (heavy-first): (64-row tile t, slice of
//   <=8 chunks). t<8 tiles are single-slice -> direct write; others write
//   (O,m,l) partials merged by merge_parts. Every SIMD keeps 2 waves busy
//   until the (tiny) last units -> no solo-block latency exposure.
// !SPLIT: grid (16, 32), R0's balanced pairing, direct writes (ws fallback).
// Pipeline per iter (R0): softmax(c) -> PV(c) -> barrier -> DMA(c+2) ->
//   QK(c+1) with packed bias (prefetched last iter) as MFMA C-init ->
//   prefetch bias(c+2). Plain launch bounds: avoid R3's spill fiasco.
template<bool SPLIT>
__global__ __launch_bounds__(256) void attn_pipe2(
    const float* __restrict__ Q,
    const __bf16* __restrict__ Kp, const __bf16* __restrict__ Vp,
    const float* __restrict__ biasp, const int* __restrict__ emask,
    float* __restrict__ out, float* __restrict__ part)
{
    __shared__ __align__(16) __bf16 Kl[2][16 * 512];   // 2 x 16KB
    __shared__ __align__(16) __bf16 Vl[2][16 * 512];   // 2 x 16KB
    __shared__ __align__(16) __bf16 Pl[4][16][72];

    const int tid  = threadIdx.x;
    const int w    = tid >> 6;
    const int lane = tid & 63;
    const int quad = lane >> 4;
    const int l15  = lane & 15;
    const int b = blockIdx.x;

    int t, c0, cend, pidx;
    bool direct;
    if (SPLIT) {
        const int u = 79 - blockIdx.y;     // heavy-first dispatch
        int s;
        if (u < 8)       { t = u;                 s = 0; }
        else if (u < 24) { t = 8  + ((u - 8) >> 1);  s = (u - 8) & 1; }
        else if (u < 48) { t = 16 + (u - 24) / 3;    s = (u - 24) % 3; }
        else             { t = 24 + ((u - 48) >> 2); s = (u - 48) & 3; }
        c0 = s * 8;
        cend = min(t + 1, c0 + 8);
        direct = (u < 8);
        pidx = u - 8;
    } else {
        const int y = blockIdx.y;
        t = (y < 16) ? y : (47 - y);       // pair sums = 33 chunks
        c0 = 0; cend = t + 1; direct = true; pidx = 0;
    }

    const int q0w = t * 64 + w * 16;
    const int t32 = t * 2 + (w >> 1);      // 32-row bias-tile index
    const int hh  = w & 1;                 // half within the bias tile
    const int fb32 = ftri(t32);

    const float*  Qb  = Q + (size_t)b * Nc * Dc;
    const __bf16* Kpb = Kp + (size_t)b * NCHUNK * CHUNK_ELEMS;
    const __bf16* Vpb = Vp + (size_t)b * NCHUNK * CHUNK_ELEMS;
    // packed bias fragments for this 16-row group, chunk c:
    //   f32x4 index (fb32+c)*512 + lane*8 + hh*4 + jt
    const f32x4* bfrag = (const f32x4*)biasp + (size_t)lane * 8 + hh * 4;

    // ---- Q fragments (emask + SCALE folded) ----
    bf16x8 qfrag[4];
    {
        const int row = q0w + l15;
        const float qs = emask[b * Nc + row] ? SCALE_F : 0.0f;
        const float4* qr = (const float4*)(Qb + (size_t)row * Dc);
        #pragma unroll
        for (int kd = 0; kd < 4; ++kd) {
            const float4 xx = qr[kd * 8 + quad * 2];
            const float4 yy = qr[kd * 8 + quad * 2 + 1];
            qfrag[kd][0] = (__bf16)(xx.x * qs); qfrag[kd][1] = (__bf16)(xx.y * qs);
            qfrag[kd][2] = (__bf16)(xx.z * qs); qfrag[kd][3] = (__bf16)(xx.w * qs);
            qfrag[kd][4] = (__bf16)(yy.x * qs); qfrag[kd][5] = (__bf16)(yy.y * qs);
            qfrag[kd][6] = (__bf16)(yy.z * qs); qfrag[kd][7] = (__bf16)(yy.w * qs);
        }
    }

    f32x4 oacc[8];
    #pragma unroll
    for (int dt = 0; dt < 8; ++dt) { oacc[dt][0]=0.f; oacc[dt][1]=0.f; oacc[dt][2]=0.f; oacc[dt][3]=0.f; }
    float mrun[4] = {-INFINITY, -INFINITY, -INFINITY, -INFINITY};
    float lrun[4] = {0.f, 0.f, 0.f, 0.f};

    const int nch = cend - c0;

    // ---- prologue: DMA chunk c0 -> buf0; bias(c0) ----
    #pragma unroll
    for (int i = 0; i < 4; ++i) {
        const int seg = w * 4 + i;
        gload_lds16(Kpb + (size_t)c0 * CHUNK_ELEMS + seg * 512 + lane * 8, &Kl[0][seg * 512]);
        gload_lds16(Vpb + (size_t)c0 * CHUNK_ELEMS + seg * 512 + lane * 8, &Vl[0][seg * 512]);
    }
    f32x4 binit[4];
    #pragma unroll
    for (int jt = 0; jt < 4; ++jt)
        binit[jt] = bfrag[(size_t)(fb32 + c0) * 512 + jt];
    __syncthreads();   // drain: chunk-c0 DMA landed

    // ---- QK(c0) with bias as C-init ----
    f32x4 sc[4];
    #pragma unroll
    for (int jt = 0; jt < 4; ++jt) sc[jt] = binit[jt];
    #pragma unroll
    for (int jt = 0; jt < 4; ++jt)
        #pragma unroll
        for (int kd = 0; kd < 4; ++kd) {
            const bf16x8 bfr = *(const bf16x8*)&Kl[0][(jt * 4 + kd) * 512 + lane * 8];
            sc[jt] = __builtin_amdgcn_mfma_f32_16x16x32_bf16(qfrag[kd], bfr, sc[jt], 0, 0, 0);
        }
    if (nch > 1) {
        #pragma unroll
        for (int i = 0; i < 4; ++i) {
            const int seg = w * 4 + i;
            gload_lds16(Kpb + (size_t)(c0 + 1) * CHUNK_ELEMS + seg * 512 + lane * 8, &Kl[1][seg * 512]);
            gload_lds16(Vpb + (size_t)(c0 + 1) * CHUNK_ELEMS + seg * 512 + lane * 8, &Vl[1][seg * 512]);
        }
        #pragma unroll
        for (int jt = 0; jt < 4; ++jt)
            binit[jt] = bfrag[(size_t)(fb32 + c0 + 1) * 512 + jt];
    }

    for (int c = c0; c < cend; ++c) {
        const int cb = (c - c0) & 1;

        // ---- causal mask on the diagonal chunk (bias already in sc) ----
        if (c == t) {
            const int m0 = c * 64;
            #pragma unroll
            for (int jt = 0; jt < 4; ++jt)
                #pragma unroll
                for (int reg = 0; reg < 4; ++reg) {
                    const int gr = q0w + quad * 4 + reg;
                    const int gc = m0 + jt * 16 + l15;
                    if (gc > gr) sc[jt][reg] = -INFINITY;
                }
        }

        // ---- online softmax (DPP 16-lane reductions; row = quad*4+reg) ----
        #pragma unroll
        for (int reg = 0; reg < 4; ++reg) {
            float mx = fmaxf(fmaxf(sc[0][reg], sc[1][reg]), fmaxf(sc[2][reg], sc[3][reg]));
            mx = rmax16(mx);
            const float mn = fmaxf(mrun[reg], mx);       // finite: diag col active
            const float alpha = __expf(mrun[reg] - mn);  // first chunk: exp(-inf)=0
            mrun[reg] = mn;
            lrun[reg] *= alpha;
            #pragma unroll
            for (int dt = 0; dt < 8; ++dt) oacc[dt][reg] *= alpha;
            float ls = 0.f;
            #pragma unroll
            for (int jt = 0; jt < 4; ++jt) {
                const float pv = __expf(sc[jt][reg] - mn);  // masked: exp(-inf)=0
                sc[jt][reg] = pv;
                ls += pv;
            }
            lrun[reg] += rsum16(ls);
        }

        // ---- P: C-layout -> LDS -> A-layout ----
        #pragma unroll
        for (int jt = 0; jt < 4; ++jt)
            #pragma unroll
            for (int reg = 0; reg < 4; ++reg)
                Pl[w][quad * 4 + reg][jt * 16 + l15] = (__bf16)sc[jt][reg];
        // same-wave write->read; compiler inserts lgkmcnt wait

        // ---- O += P V ----
        #pragma unroll
        for (int kj = 0; kj < 2; ++kj) {
            const bf16x8 pa = *(const bf16x8*)&Pl[w][l15][kj * 32 + quad * 8];
            #pragma unroll
            for (int dt = 0; dt < 8; ++dt) {
                const bf16x8 vb = *(const bf16x8*)&Vl[cb][(kj * 8 + dt) * 512 + lane * 8];
                oacc[dt] = __builtin_amdgcn_mfma_f32_16x16x32_bf16(pa, vb, oacc[dt], 0, 0, 0);
            }
        }

        // single barrier: all waves done reading Kl[cb]/Vl[cb]; vmcnt drain
        // covers DMA(c+1) (issued a full iteration ago -> near-free).
        __syncthreads();

        const bool n1 = (c + 1) < cend;
        const bool n2 = (c + 2) < cend;

        // ---- DMA chunk c+2 into buf[cb] (K(c)/V(c) both retired) ----
        if (n2) {
            const size_t off = (size_t)(c + 2) * CHUNK_ELEMS;
            #pragma unroll
            for (int i = 0; i < 4; ++i) {
                const int seg = w * 4 + i;
                gload_lds16(Kpb + off + seg * 512 + lane * 8, &Kl[cb][seg * 512]);
                gload_lds16(Vpb + off + seg * 512 + lane * 8, &Vl[cb][seg * 512]);
            }
        }

        // ---- QK(c+1) from Kl[cb^1]; bias (prefetched last iter) as C-init ----
        if (n1) {
            #pragma unroll
            for (int jt = 0; jt < 4; ++jt) sc[jt] = binit[jt];
            #pragma unroll
            for (int jt = 0; jt < 4; ++jt)
                #pragma unroll
                for (int kd = 0; kd < 4; ++kd) {
                    const bf16x8 bfr = *(const bf16x8*)&Kl[cb ^ 1][(jt * 4 + kd) * 512 + lane * 8];
                    sc[jt] = __builtin_amdgcn_mfma_f32_16x16x32_bf16(qfrag[kd], bfr, sc[jt], 0, 0, 0);
                }
        }
        if (n2) {
            #pragma unroll
            for (int jt = 0; jt < 4; ++jt)
                binit[jt] = bfrag[(size_t)(fb32 + c + 2) * 512 + jt];
        }
    }

    // ---- epilogue ----
    if (direct) {
        #pragma unroll
        for (int reg = 0; reg < 4; ++reg) {
            const float inv = 1.0f / lrun[reg];
            const int gr = q0w + quad * 4 + reg;
            float* orow = out + ((size_t)b * Nc + gr) * Dc;
            #pragma unroll
            for (int dt = 0; dt < 8; ++dt)
                orow[dt * 16 + l15] = oacc[dt][reg] * inv;
        }
    } else {
        float* pb = part + (size_t)(b * 72 + pidx) * PART_FLOATS;
        #pragma unroll
        for (int reg = 0; reg < 4; ++reg) {
            const int lr = w * 16 + quad * 4 + reg;
            #pragma unroll
            for (int dt = 0; dt < 8; ++dt)
                pb[lr * 128 + dt * 16 + l15] = oacc[dt][reg];
            if (l15 == 0) {
                pb[8192 + lr] = mrun[reg];
                pb[8256 + lr] = lrun[reg];
            }
        }
    }
}

// ---- merge <=4 split-C partials per (b, tile t=8..31) ----
__global__ __launch_bounds__(256) void merge_parts(
    const float* __restrict__ part, float* __restrict__ out)
{
    const int b = blockIdx.x;
    const int t = 8 + blockIdx.y;
    const int S = (t < 16) ? 2 : ((t < 24) ? 3 : 4);
    const int pbase = (t < 16) ? 2 * (t - 8)
                    : (t < 24) ? 16 + 3 * (t - 16)
                               : 40 + 4 * (t - 24);
    const int r  = threadIdx.x >> 2;       // row 0..63
    const int cq = threadIdx.x & 3;        // col quarter (32 cols)
    const float* p0 = part + (size_t)(b * 72 + pbase) * PART_FLOATS;

    float m[4], a[4];
    float mstar = -INFINITY;
    #pragma unroll
    for (int s = 0; s < 4; ++s)
        if (s < S) { m[s] = p0[(size_t)s * PART_FLOATS + 8192 + r]; mstar = fmaxf(mstar, m[s]); }
    float lsum = 0.f;
    #pragma unroll
    for (int s = 0; s < 4; ++s)
        if (s < S) {
            a[s] = __expf(m[s] - mstar);
            lsum += p0[(size_t)s * PART_FLOATS + 8256 + r] * a[s];
        }
    const float inv = 1.0f / lsum;

    float* orow = out + ((size_t)b * Nc + t * 64 + r) * Dc + cq * 32;
    #pragma unroll
    for (int i = 0; i < 8; ++i) {
        float x = 0.f, y = 0.f, z = 0.f, ww = 0.f;
        #pragma unroll
        for (int s = 0; s < 4; ++s)
            if (s < S) {
                const f32x4 v = *(const f32x4*)&p0[(size_t)s * PART_FLOATS + r * 128 + cq * 32 + i * 4];
                x += v[0] * a[s]; y += v[1] * a[s]; z += v[2] * a[s]; ww += v[3] * a[s];
            }
        f32x4 o; o[0] = x * inv; o[1] = y * inv; o[2] = z * inv; o[3] = ww * inv;
        *(f32x4*)&orow[i * 4] = o;
    }
}

// ---- legacy fallback (in-kernel staging, 4 bias reads) for tiny ws ----
__global__ __launch_bounds__(256) void attn_mfma_legacy(
    const float* __restrict__ Q, const float* __restrict__ K, const float* __restrict__ V,
    const float* __restrict__ p0, const float* __restrict__ p1,
    const float* __restrict__ p2, const float* __restrict__ p3,
    const int* __restrict__ imask, const int* __restrict__ emask,
    float* __restrict__ out)
{
    __shared__ __align__(16) __bf16 Klds[64][136];
    __shared__ __align__(16) __bf16 Vt[128][72];
    __shared__ __align__(16) __bf16 Plds[4][16][72];
    const int tid  = threadIdx.x;
    const int w    = tid >> 6;
    const int lane = tid & 63;
    const int quad = lane >> 4;
    const int l15  = lane & 15;
    const int b = blockIdx.y;
    const int x = blockIdx.x, yy = blockIdx.y;
    const int ti = (yy < 8) ? x : (31 - x);
    const int q0 = ti * 64, q0w = q0 + w * 16;
    const float* Qb = Q + (size_t)b * Nc * Dc;
    const float* Kb = K + (size_t)b * Nc * Dc;
    const float* Vb = V + (size_t)b * Nc * Dc;
    const int* imb = imask + b * Nc;

    bf16x8 qfrag[4];
    {
        const int row = q0w + l15;
        const float qs = emask[b * Nc + row] ? SCALE_F : 0.0f;
        const float4* qr = (const float4*)(Qb + (size_t)row * Dc);
        #pragma unroll
        for (int kd = 0; kd < 4; ++kd) {
            const float4 xv = qr[kd * 8 + quad * 2];
            const float4 yv = qr[kd * 8 + quad * 2 + 1];
            qfrag[kd][0]=(__bf16)(xv.x*qs); qfrag[kd][1]=(__bf16)(xv.y*qs);
            qfrag[kd][2]=(__bf16)(xv.z*qs); qfrag[kd][3]=(__bf16)(xv.w*qs);
            qfrag[kd][4]=(__bf16)(yv.x*qs); qfrag[kd][5]=(__bf16)(yv.y*qs);
            qfrag[kd][6]=(__bf16)(yv.z*qs); qfrag[kd][7]=(__bf16)(yv.w*qs);
        }
    }
    f32x4 oacc[8];
    #pragma unroll
    for (int dt = 0; dt < 8; ++dt){oacc[dt][0]=0.f;oacc[dt][1]=0.f;oacc[dt][2]=0.f;oacc[dt][3]=0.f;}
    float mrun[4]={-INFINITY,-INFINITY,-INFINITY,-INFINITY}, lrun[4]={0.f,0.f,0.f,0.f};

    for (int m0 = 0; m0 <= q0; m0 += 64) {
        __syncthreads();
        #pragma unroll
        for (int it = 0; it < 8; ++it) {
            const int idx = it * 256 + tid;
            const int row = idx >> 5, c4 = idx & 31;
            const int gm = m0 + row;
            const float msk = imb[gm] ? 1.0f : 0.0f;
            const float4 kf = ((const float4*)(Kb + (size_t)gm * Dc))[c4];
            const float4 vf = ((const float4*)(Vb + (size_t)gm * Dc))[c4];
            bf16x4 kb;
            kb[0]=(__bf16)(kf.x*msk); kb[1]=(__bf16)(kf.y*msk);
            kb[2]=(__bf16)(kf.z*msk); kb[3]=(__bf16)(kf.w*msk);
            *(bf16x4*)&Klds[row][c4*4] = kb;
            Vt[c4*4+0][row]=(__bf16)(vf.x*msk); Vt[c4*4+1][row]=(__bf16)(vf.y*msk);
            Vt[c4*4+2][row]=(__bf16)(vf.z*msk); Vt[c4*4+3][row]=(__bf16)(vf.w*msk);
        }
        __syncthreads();
        f32x4 sc[4];
        #pragma unroll
        for (int jt = 0; jt < 4; ++jt){sc[jt][0]=0.f;sc[jt][1]=0.f;sc[jt][2]=0.f;sc[jt][3]=0.f;}
        #pragma unroll
        for (int jt = 0; jt < 4; ++jt)
            #pragma unroll
            for (int kd = 0; kd < 4; ++kd) {
                const bf16x8 bfr = *(const bf16x8*)&Klds[jt*16+l15][kd*32+quad*8];
                sc[jt] = __builtin_amdgcn_mfma_f32_16x16x32_bf16(qfrag[kd], bfr, sc[jt], 0, 0, 0);
            }
        #pragma unroll
        for (int jt = 0; jt < 4; ++jt)
            #pragma unroll
            for (int reg = 0; reg < 4; ++reg) {
                const int gr = q0w + quad*4 + reg;
                const int gc = m0 + jt*16 + l15;
                const size_t boff = (size_t)gr * Nc + gc;
                const float bsx = p0[boff] + p1[boff] + p2[boff] + p3[boff];
                const float v = sc[jt][reg] + bsx;
                sc[jt][reg] = (gc > gr) ? -INFINITY : v;
            }
        #pragma unroll
        for (int reg = 0; reg < 4; ++reg) {
            float mx = fmaxf(fmaxf(sc[0][reg], sc[1][reg]), fmaxf(sc[2][reg], sc[3][reg]));
            mx = rmax16(mx);
            const float mn = fmaxf(mrun[reg], mx);
            const float alpha = __expf(mrun[reg] - mn);
            mrun[reg] = mn; lrun[reg] *= alpha;
            #pragma unroll
            for (int dt = 0; dt < 8; ++dt) oacc[dt][reg] *= alpha;
            float ls = 0.f;
            #pragma unroll
            for (int jt = 0; jt < 4; ++jt) {
                const float pv = __expf(sc[jt][reg] - mn);
                sc[jt][reg] = pv; ls += pv;
            }
            lrun[reg] += rsum16(ls);
        }
        #pragma unroll
        for (int jt = 0; jt < 4; ++jt)
            #pragma unroll
            for (int reg = 0; reg < 4; ++reg)
                Plds[w][quad*4+reg][jt*16+l15] = (__bf16)sc[jt][reg];
        #pragma unroll
        for (int kj = 0; kj < 2; ++kj) {
            const bf16x8 pa = *(const bf16x8*)&Plds[w][l15][kj*32+quad*8];
            #pragma unroll
            for (int dt = 0; dt < 8; ++dt) {
                const bf16x8 vb = *(const bf16x8*)&Vt[dt*16+l15][kj*32+quad*8];
                oacc[dt] = __builtin_amdgcn_mfma_f32_16x16x32_bf16(pa, vb, oacc[dt], 0, 0, 0);
            }
        }
    }
    #pragma unroll
    for (int reg = 0; reg < 4; ++reg) {
        const float inv = 1.0f / lrun[reg];
        const int gr = q0w + quad*4 + reg;
        float* orow = out + ((size_t)b * Nc + gr) * Dc;
        #pragma unroll
        for (int dt = 0; dt < 8; ++dt)
            orow[dt*16+l15] = oacc[dt][reg] * inv;
    }
}

extern "C" void kernel_launch(void* const* d_in, const int* in_sizes, int n_in,
                              void* d_out, int out_size, void* d_ws, size_t ws_size,
                              hipStream_t stream) {
    const float* Q  = (const float*)d_in[0];
    const float* K  = (const float*)d_in[1];
    const float* V  = (const float*)d_in[2];
    const float* b0 = (const float*)d_in[3];
    const float* b1 = (const float*)d_in[4];
    const float* b2 = (const float*)d_in[5];
    const float* b3 = (const float*)d_in[6];
    const int* im   = (const int*)d_in[7];
    const int* em   = (const int*)d_in[8];
    float* out      = (float*)d_out;

    const size_t need_full  = KPACK_BYTES + VPACK_BYTES + BIASP_BYTES;
    const size_t need_split = need_full + PART_BYTES;

    if (ws_size >= need_full) {
        __bf16* Kp  = (__bf16*)d_ws;
        __bf16* Vp  = (__bf16*)((char*)d_ws + KPACK_BYTES);
        float*  bsp = (float*)((char*)d_ws + KPACK_BYTES + VPACK_BYTES);
        float*  prt = (float*)((char*)d_ws + need_full);
        prep_fused<<<512 + NUNITS, 256, 0, stream>>>(
            K, V, im, b0, b1, b2, b3, Kp, Vp, bsp);
        if (ws_size >= need_split) {
            attn_pipe2<true><<<dim3(Bc, 80), 256, 0, stream>>>(
                Q, Kp, Vp, bsp, em, out, prt);
            merge_parts<<<dim3(Bc, 24), 256, 0, stream>>>(prt, out);
        } else {
            attn_pipe2<false><<<dim3(Bc, 32), 256, 0, stream>>>(
                Q, Kp, Vp, bsp, em, out, nullptr);
        }
    } else {
        attn_mfma_legacy<<<dim3(NCHUNK, Bc), 256, 0, stream>>>(
            Q, K, V, b0, b1, b2, b3, im, em, out);
    }
}